// Round 1
// baseline (875.768 us; speedup 1.0000x reference)
//
#include <hip/hip_runtime.h>
#include <hip/hip_bf16.h>

#define N_NODES 50000
#define N_EDGES 800000
#define N_GRAPHS 128

// ---------------- CSR build ----------------

__global__ void count_kernel(const int* __restrict__ dst, int* __restrict__ counts, int E) {
    int e = blockIdx.x * blockDim.x + threadIdx.x;
    if (e < E) atomicAdd(&counts[dst[e]], 1);
}

__global__ __launch_bounds__(1024) void scan_kernel(const int* __restrict__ cnt,
                                                    int* __restrict__ row_ptr,
                                                    int* __restrict__ cursor, int n) {
    __shared__ int part[1024];
    int t = threadIdx.x;
    const int CH = (n + 1023) >> 10;  // 49
    int base = t * CH;
    int s = 0;
    for (int i = 0; i < CH; ++i) {
        int j = base + i;
        if (j < n) s += cnt[j];
    }
    part[t] = s;
    __syncthreads();
    // Hillis-Steele inclusive scan over 1024 partials
    for (int off = 1; off < 1024; off <<= 1) {
        int add = (t >= off) ? part[t - off] : 0;
        __syncthreads();
        part[t] += add;
        __syncthreads();
    }
    int run = part[t] - s;  // exclusive prefix of this chunk
    for (int i = 0; i < CH; ++i) {
        int j = base + i;
        if (j < n) {
            row_ptr[j] = run;
            cursor[j] = run;
            run += cnt[j];
        }
    }
    if (t == 1023) row_ptr[n] = part[1023];
}

__global__ void fill_kernel(const int* __restrict__ dst, const int* __restrict__ src,
                            const float* __restrict__ w, int* __restrict__ cursor,
                            int* __restrict__ srcs_r, float* __restrict__ wts_r, int E) {
    int e = blockIdx.x * blockDim.x + threadIdx.x;
    if (e < E) {
        int d = dst[e];
        int p = atomicAdd(&cursor[d], 1);
        srcs_r[p] = src[e];
        wts_r[p] = w[e];
    }
}

// ---------------- graph segment boundaries (graph_ids sorted) ----------------

__global__ void bounds_kernel(const int* __restrict__ gid, int* __restrict__ start,
                              int n, int ngraphs) {
    int i = blockIdx.x * blockDim.x + threadIdx.x;
    if (i >= n) return;
    int g = gid[i];
    if (i == 0) {
        for (int q = 0; q <= g; ++q) start[q] = 0;
    } else {
        int p = gid[i - 1];
        if (p != g) {
            for (int q = p + 1; q <= g; ++q) start[q] = i;
        }
    }
    if (i == n - 1) {
        for (int q = g + 1; q <= ngraphs; ++q) start[q] = n;
    }
}

// ---------------- edge aggregation: one wave per node ----------------

__global__ __launch_bounds__(256) void agg_kernel(const float* __restrict__ h,
                                                  const float* __restrict__ wts,
                                                  const int* __restrict__ srcs,
                                                  const int* __restrict__ row_ptr,
                                                  const float* __restrict__ eps, int layer,
                                                  float* __restrict__ out, int n) {
    int node = blockIdx.x * 4 + (threadIdx.x >> 6);
    int d = threadIdx.x & 63;
    if (node >= n) return;
    float e1 = 1.0f + eps[layer];
    float acc = e1 * h[(size_t)node * 64 + d];
    int j = row_ptr[node];
    int j1 = row_ptr[node + 1];
    for (; j + 1 < j1; j += 2) {
        int s0 = srcs[j];
        int s1 = srcs[j + 1];
        float w0 = wts[j];
        float w1 = wts[j + 1];
        acc += w0 * h[(size_t)s0 * 64 + d];
        acc += w1 * h[(size_t)s1 * 64 + d];
    }
    if (j < j1) acc += wts[j] * h[(size_t)srcs[j] * 64 + d];
    out[(size_t)node * 64 + d] = acc;
}

// ---------------- 64-wide GEMM with fused BN-stat accumulation ----------------
// out[r][c] = (transform? relu(bn(A[r][:])) : A[r][:]) @ W + bias, and
// atomically accumulates column sum / sumsq of OUT into stats_out[0:64]/[64:128].

#define TILE_ROWS 128

__global__ __launch_bounds__(256) void gin_gemm64(const float* __restrict__ A,
                                                  const float* __restrict__ W,
                                                  const float* __restrict__ bias,
                                                  float* __restrict__ out,
                                                  float* __restrict__ stats_out,
                                                  const float* __restrict__ stats_in,
                                                  const float* __restrict__ gamma,
                                                  const float* __restrict__ beta,
                                                  int n, int transform) {
    __shared__ float smem[TILE_ROWS * 64 + 64 * 64 + 128];
    float* As = smem;                   // swizzled [128][64]
    float* Ws = smem + TILE_ROWS * 64;  // [64][64]
    float* sc = Ws + 4096;
    float* sh = sc + 64;

    const int t = threadIdx.x;
    const int rowbase = blockIdx.x * TILE_ROWS;

    if (transform && t < 64) {
        float inv_n = 1.0f / (float)n;
        float mean = stats_in[t] * inv_n;
        float var = stats_in[64 + t] * inv_n - mean * mean;
        float s = gamma[t] * rsqrtf(var + 1e-5f);
        sc[t] = s;
        sh[t] = beta[t] - mean * s;
    }
    __syncthreads();

    // stage A tile (swizzled on k-chunks to kill bank conflicts) and W
    for (int idx = t; idx < TILE_ROWS * 16; idx += 256) {
        int r = idx >> 4;
        int k4 = (idx & 15) << 2;
        int gr = rowbase + r;
        float4 v = make_float4(0.f, 0.f, 0.f, 0.f);
        if (gr < n) v = *(const float4*)(A + (size_t)gr * 64 + k4);
        if (transform) {
            v.x = fmaxf(fmaf(v.x, sc[k4 + 0], sh[k4 + 0]), 0.f);
            v.y = fmaxf(fmaf(v.y, sc[k4 + 1], sh[k4 + 1]), 0.f);
            v.z = fmaxf(fmaf(v.z, sc[k4 + 2], sh[k4 + 2]), 0.f);
            v.w = fmaxf(fmaf(v.w, sc[k4 + 3], sh[k4 + 3]), 0.f);
        }
        int pc = (k4 >> 2) ^ ((r >> 3) & 3);
        *(float4*)(As + r * 64 + (pc << 2)) = v;
    }
    for (int idx = t; idx < 1024; idx += 256) {
        *(float4*)(Ws + (idx << 2)) = *(const float4*)(W + (idx << 2));
    }
    __syncthreads();

    const int ci = t & 15;
    const int ri = t >> 4;  // 0..15, rows ri*8 .. ri*8+7
    const int c0 = ci << 2;

    float acc[8][4];
#pragma unroll
    for (int i = 0; i < 8; ++i) acc[i][0] = acc[i][1] = acc[i][2] = acc[i][3] = 0.f;

    const int pcx = ri & 3;  // (r>>3)&3 is constant (=ri) for this thread's rows
#pragma unroll 2
    for (int k4 = 0; k4 < 64; k4 += 4) {
        float4 wv[4];
        wv[0] = *(const float4*)(Ws + (k4 + 0) * 64 + c0);
        wv[1] = *(const float4*)(Ws + (k4 + 1) * 64 + c0);
        wv[2] = *(const float4*)(Ws + (k4 + 2) * 64 + c0);
        wv[3] = *(const float4*)(Ws + (k4 + 3) * 64 + c0);
        int pc = (k4 >> 2) ^ pcx;
#pragma unroll
        for (int i = 0; i < 8; ++i) {
            int r = ri * 8 + i;
            float4 av = *(const float4*)(As + r * 64 + (pc << 2));
            acc[i][0] += av.x * wv[0].x + av.y * wv[1].x + av.z * wv[2].x + av.w * wv[3].x;
            acc[i][1] += av.x * wv[0].y + av.y * wv[1].y + av.z * wv[2].y + av.w * wv[3].y;
            acc[i][2] += av.x * wv[0].z + av.y * wv[1].z + av.z * wv[2].z + av.w * wv[3].z;
            acc[i][3] += av.x * wv[0].w + av.y * wv[1].w + av.z * wv[2].w + av.w * wv[3].w;
        }
    }

    float bv0 = bias[c0 + 0], bv1 = bias[c0 + 1], bv2 = bias[c0 + 2], bv3 = bias[c0 + 3];
    float psum[4] = {0, 0, 0, 0}, psq[4] = {0, 0, 0, 0};
#pragma unroll
    for (int i = 0; i < 8; ++i) {
        int gr = rowbase + ri * 8 + i;
        if (gr < n) {
            float o0 = acc[i][0] + bv0;
            float o1 = acc[i][1] + bv1;
            float o2 = acc[i][2] + bv2;
            float o3 = acc[i][3] + bv3;
            *(float4*)(out + (size_t)gr * 64 + c0) = make_float4(o0, o1, o2, o3);
            psum[0] += o0; psq[0] += o0 * o0;
            psum[1] += o1; psq[1] += o1 * o1;
            psum[2] += o2; psq[2] += o2 * o2;
            psum[3] += o3; psq[3] += o3 * o3;
        }
    }

    // block reduction of column stats (alias over Ws region, stride 17 to avoid conflicts)
    __syncthreads();
    float* rsum = Ws;
    float* rsq = Ws + 64 * 17;
#pragma unroll
    for (int j = 0; j < 4; ++j) {
        rsum[(c0 + j) * 17 + ri] = psum[j];
        rsq[(c0 + j) * 17 + ri] = psq[j];
    }
    __syncthreads();
    if (t < 64) {
        float s = 0.f, q = 0.f;
#pragma unroll
        for (int i = 0; i < 16; ++i) {
            s += rsum[t * 17 + i];
            q += rsq[t * 17 + i];
        }
        atomicAdd(&stats_out[t], s);
        atomicAdd(&stats_out[64 + t], q);
    }
}

// ---------------- elementwise outer BN + ReLU (in place) ----------------

__global__ __launch_bounds__(256) void bn_relu_kernel(float* __restrict__ h,
                                                      const float* __restrict__ stats,
                                                      const float* __restrict__ gamma,
                                                      const float* __restrict__ beta,
                                                      int n, int n4) {
    __shared__ float sc[64], sh[64];
    int t = threadIdx.x;
    if (t < 64) {
        float inv_n = 1.0f / (float)n;
        float mean = stats[t] * inv_n;
        float var = stats[64 + t] * inv_n - mean * mean;
        float s = gamma[t] * rsqrtf(var + 1e-5f);
        sc[t] = s;
        sh[t] = beta[t] - mean * s;
    }
    __syncthreads();
    int idx = blockIdx.x * blockDim.x + t;
    if (idx < n4) {
        int k0 = (idx & 15) << 2;
        float4 v = *(const float4*)(h + (size_t)idx * 4);
        v.x = fmaxf(fmaf(v.x, sc[k0 + 0], sh[k0 + 0]), 0.f);
        v.y = fmaxf(fmaf(v.y, sc[k0 + 1], sh[k0 + 1]), 0.f);
        v.z = fmaxf(fmaf(v.z, sc[k0 + 2], sh[k0 + 2]), 0.f);
        v.w = fmaxf(fmaf(v.w, sc[k0 + 3], sh[k0 + 3]), 0.f);
        *(float4*)(h + (size_t)idx * 4) = v;
    }
}

// ---------------- pooled readout over sorted segments ----------------

__global__ __launch_bounds__(256) void pool_kernel(const float* __restrict__ h,
                                                   const int* __restrict__ start,
                                                   float* __restrict__ pool) {
    int g = blockIdx.x;
    int d = threadIdx.x & 63;
    int sub = threadIdx.x >> 6;
    int i0 = start[g], i1 = start[g + 1];
    float acc = 0.f;
    for (int i = i0 + sub; i < i1; i += 4) acc += h[(size_t)i * 64 + d];
    __shared__ float red[4][64];
    red[sub][d] = acc;
    __syncthreads();
    int t = threadIdx.x;
    if (t < 64) pool[g * 64 + t] = red[0][t] + red[1][t] + red[2][t] + red[3][t];
}

__global__ __launch_bounds__(256) void score_kernel(const float* __restrict__ pool,
                                                    const float* __restrict__ pW,
                                                    const float* __restrict__ pb,
                                                    float* __restrict__ score, int accumulate) {
    int idx = blockIdx.x * blockDim.x + threadIdx.x;
    if (idx >= N_GRAPHS * 16) return;
    int g = idx >> 4;
    int o = idx & 15;
    float s = pb[o];
#pragma unroll 8
    for (int d = 0; d < 64; ++d) s += pool[g * 64 + d] * pW[d * 16 + o];
    score[idx] = accumulate ? (score[idx] + s) : s;
}

// ---------------- host ----------------

extern "C" void kernel_launch(void* const* d_in, const int* in_sizes, int n_in,
                              void* d_out, int out_size, void* d_ws, size_t ws_size,
                              hipStream_t stream) {
    const float* x = (const float*)d_in[0];
    const float* w = (const float*)d_in[1];
    const int* src = (const int*)d_in[2];
    const int* dst = (const int*)d_in[3];
    const int* gid = (const int*)d_in[4];
    const float* eps = (const float*)d_in[5];
    const float* W1 = (const float*)d_in[6];
    const float* b1 = (const float*)d_in[7];
    const float* bng = (const float*)d_in[8];
    const float* bnb = (const float*)d_in[9];
    const float* W2 = (const float*)d_in[10];
    const float* b2 = (const float*)d_in[11];
    const float* og = (const float*)d_in[12];
    const float* ob = (const float*)d_in[13];
    const float* pW = (const float*)d_in[14];
    const float* pb = (const float*)d_in[15];
    float* out = (float*)d_out;

    const int N = N_NODES, E = N_EDGES, G = N_GRAPHS;

    float* base = (float*)d_ws;
    float* HA = base;                      // N*64
    float* HB = HA + (size_t)N * 64;       // N*64
    float* stats = HB + (size_t)N * 64;    // 1024 (zeroed): 4 layers x 2 BNs x 128
    int* counts = (int*)(stats + 1024);    // N (zeroed)
    int* row_ptr = counts + N;             // N+1 (pad 4)
    int* cursor = row_ptr + N + 4;         // N+1 (pad 4)
    int* srcs_r = cursor + N + 4;          // E
    float* wts_r = (float*)(srcs_r + E);   // E
    int* start = (int*)(wts_r + E);        // G+1 (pad to 132)
    float* pool = (float*)(start + 132);   // G*64

    // one upfront zeroing of everything that is accumulated into
    hipMemsetAsync(stats, 0, (size_t)(1024 + N) * sizeof(float), stream);

    // CSR build (once per launch, reused by 4 layers)
    hipLaunchKernelGGL(count_kernel, dim3((E + 255) / 256), dim3(256), 0, stream, dst, counts, E);
    hipLaunchKernelGGL(scan_kernel, dim3(1), dim3(1024), 0, stream, counts, row_ptr, cursor, N);
    hipLaunchKernelGGL(fill_kernel, dim3((E + 255) / 256), dim3(256), 0, stream, dst, src, w,
                       cursor, srcs_r, wts_r, E);
    hipLaunchKernelGGL(bounds_kernel, dim3((N + 255) / 256), dim3(256), 0, stream, gid, start, N, G);

    // layer-0 score on raw features
    hipLaunchKernelGGL(pool_kernel, dim3(G), dim3(256), 0, stream, x, start, pool);
    hipLaunchKernelGGL(score_kernel, dim3(8), dim3(256), 0, stream, pool, pW, pb, out, 0);

    const float* cur = x;
    float* P = HA;
    float* Q = HB;
    for (int l = 0; l < 4; ++l) {
        hipLaunchKernelGGL(agg_kernel, dim3((N + 3) / 4), dim3(256), 0, stream, cur, wts_r, srcs_r,
                           row_ptr, eps, l, P, N);
        hipLaunchKernelGGL(gin_gemm64, dim3((N + TILE_ROWS - 1) / TILE_ROWS), dim3(256), 0, stream,
                           P, W1 + l * 4096, b1 + l * 64, Q, stats + l * 256,
                           (const float*)nullptr, (const float*)nullptr, (const float*)nullptr, N, 0);
        hipLaunchKernelGGL(gin_gemm64, dim3((N + TILE_ROWS - 1) / TILE_ROWS), dim3(256), 0, stream,
                           Q, W2 + l * 4096, b2 + l * 64, P, stats + l * 256 + 128,
                           stats + l * 256, bng + l * 64, bnb + l * 64, N, 1);
        hipLaunchKernelGGL(bn_relu_kernel, dim3((N * 16 + 255) / 256), dim3(256), 0, stream, P,
                           stats + l * 256 + 128, og + l * 64, ob + l * 64, N, N * 16);
        hipLaunchKernelGGL(pool_kernel, dim3(G), dim3(256), 0, stream, P, start, pool);
        hipLaunchKernelGGL(score_kernel, dim3(8), dim3(256), 0, stream, pool, pW + (l + 1) * 1024,
                           pb + (l + 1) * 16, out, 1);
        cur = P;
        float* tmp = P;
        P = Q;
        Q = tmp;
    }
}

// Round 2
// 604.470 us; speedup vs baseline: 1.4488x; 1.4488x over previous
//
#include <hip/hip_runtime.h>
#include <hip/hip_bf16.h>

#define N_NODES 50000
#define N_EDGES 800000
#define N_GRAPHS 128
#define SCAN_BLOCKS ((N_NODES + 255) / 256)  // 196

// ---------------- CSR build ----------------

__global__ void count_kernel(const int* __restrict__ dst, int* __restrict__ counts, int E) {
    int e = blockIdx.x * blockDim.x + threadIdx.x;
    if (e < E) atomicAdd(&counts[dst[e]], 1);
}

// phase 1: per-block sums of counts
__global__ __launch_bounds__(256) void bsum_kernel(const int* __restrict__ cnt,
                                                   int* __restrict__ bsum, int n) {
    __shared__ int red[256];
    int t = threadIdx.x;
    int i = blockIdx.x * 256 + t;
    red[t] = (i < n) ? cnt[i] : 0;
    __syncthreads();
    for (int off = 128; off > 0; off >>= 1) {
        if (t < off) red[t] += red[t + off];
        __syncthreads();
    }
    if (t == 0) bsum[blockIdx.x] = red[0];
}

// phase 2: exclusive scan of block sums (single block, nb <= 256)
__global__ __launch_bounds__(256) void bscan_kernel(int* __restrict__ bsum, int nb) {
    __shared__ int s[256];
    int t = threadIdx.x;
    int orig = (t < nb) ? bsum[t] : 0;
    s[t] = orig;
    __syncthreads();
    for (int off = 1; off < 256; off <<= 1) {
        int v = (t >= off) ? s[t - off] : 0;
        __syncthreads();
        s[t] += v;
        __syncthreads();
    }
    if (t < nb) bsum[t] = s[t] - orig;  // exclusive
}

// phase 3: block-local scan + block offset -> row_ptr / cursor
__global__ __launch_bounds__(256) void bwrite_kernel(const int* __restrict__ cnt,
                                                     const int* __restrict__ boff,
                                                     int* __restrict__ row_ptr,
                                                     int* __restrict__ cursor, int n) {
    __shared__ int s[256];
    int t = threadIdx.x;
    int i = blockIdx.x * 256 + t;
    int v = (i < n) ? cnt[i] : 0;
    s[t] = v;
    __syncthreads();
    for (int off = 1; off < 256; off <<= 1) {
        int u = (t >= off) ? s[t - off] : 0;
        __syncthreads();
        s[t] += u;
        __syncthreads();
    }
    int excl = s[t] - v + boff[blockIdx.x];
    if (i < n) {
        row_ptr[i] = excl;
        cursor[i] = excl;
        if (i == n - 1) row_ptr[n] = excl + v;
    }
}

__global__ void fill_kernel(const int* __restrict__ dst, const int* __restrict__ src,
                            const float* __restrict__ w, int* __restrict__ cursor,
                            int2* __restrict__ pack, int E) {
    int e = blockIdx.x * blockDim.x + threadIdx.x;
    if (e < E) {
        int d = dst[e];
        int p = atomicAdd(&cursor[d], 1);
        pack[p] = make_int2(src[e], __float_as_int(w[e]));
    }
}

// ---------------- graph segment boundaries (graph_ids sorted) ----------------

__global__ void bounds_kernel(const int* __restrict__ gid, int* __restrict__ start,
                              int n, int ngraphs) {
    int i = blockIdx.x * blockDim.x + threadIdx.x;
    if (i >= n) return;
    int g = gid[i];
    if (i == 0) {
        for (int q = 0; q <= g; ++q) start[q] = 0;
    } else {
        int p = gid[i - 1];
        if (p != g) {
            for (int q = p + 1; q <= g; ++q) start[q] = i;
        }
    }
    if (i == n - 1) {
        for (int q = g + 1; q <= ngraphs; ++q) start[q] = n;
    }
}

// ---------------- edge aggregation: one wave per node ----------------

__global__ __launch_bounds__(256) void agg_kernel(const float* __restrict__ h,
                                                  const int2* __restrict__ pack,
                                                  const int* __restrict__ row_ptr,
                                                  const float* __restrict__ eps, int layer,
                                                  float* __restrict__ out, int n) {
    int node = blockIdx.x * 4 + (threadIdx.x >> 6);
    int d = threadIdx.x & 63;
    if (node >= n) return;
    float e1 = 1.0f + eps[layer];
    float acc = e1 * h[(size_t)node * 64 + d];
    int j = row_ptr[node];
    int j1 = row_ptr[node + 1];
    for (; j + 3 < j1; j += 4) {
        int2 p0 = pack[j];
        int2 p1 = pack[j + 1];
        int2 p2 = pack[j + 2];
        int2 p3 = pack[j + 3];
        float h0 = h[(size_t)p0.x * 64 + d];
        float h1 = h[(size_t)p1.x * 64 + d];
        float h2 = h[(size_t)p2.x * 64 + d];
        float h3 = h[(size_t)p3.x * 64 + d];
        acc += __int_as_float(p0.y) * h0;
        acc += __int_as_float(p1.y) * h1;
        acc += __int_as_float(p2.y) * h2;
        acc += __int_as_float(p3.y) * h3;
    }
    for (; j < j1; ++j) {
        int2 p = pack[j];
        acc += __int_as_float(p.y) * h[(size_t)p.x * 64 + d];
    }
    out[(size_t)node * 64 + d] = acc;
}

// ---------------- 64-wide GEMM with fused BN-stat accumulation ----------------

#define TILE_ROWS 128

__global__ __launch_bounds__(256) void gin_gemm64(const float* __restrict__ A,
                                                  const float* __restrict__ W,
                                                  const float* __restrict__ bias,
                                                  float* __restrict__ out,
                                                  float* __restrict__ stats_out,
                                                  const float* __restrict__ stats_in,
                                                  const float* __restrict__ gamma,
                                                  const float* __restrict__ beta,
                                                  int n, int transform) {
    __shared__ float smem[TILE_ROWS * 64 + 64 * 64 + 128];
    float* As = smem;                   // swizzled [128][64]
    float* Ws = smem + TILE_ROWS * 64;  // [64][64]
    float* sc = Ws + 4096;
    float* sh = sc + 64;

    const int t = threadIdx.x;
    const int rowbase = blockIdx.x * TILE_ROWS;

    if (transform && t < 64) {
        float inv_n = 1.0f / (float)n;
        float mean = stats_in[t] * inv_n;
        float var = stats_in[64 + t] * inv_n - mean * mean;
        float s = gamma[t] * rsqrtf(var + 1e-5f);
        sc[t] = s;
        sh[t] = beta[t] - mean * s;
    }
    __syncthreads();

    for (int idx = t; idx < TILE_ROWS * 16; idx += 256) {
        int r = idx >> 4;
        int k4 = (idx & 15) << 2;
        int gr = rowbase + r;
        float4 v = make_float4(0.f, 0.f, 0.f, 0.f);
        if (gr < n) v = *(const float4*)(A + (size_t)gr * 64 + k4);
        if (transform) {
            v.x = fmaxf(fmaf(v.x, sc[k4 + 0], sh[k4 + 0]), 0.f);
            v.y = fmaxf(fmaf(v.y, sc[k4 + 1], sh[k4 + 1]), 0.f);
            v.z = fmaxf(fmaf(v.z, sc[k4 + 2], sh[k4 + 2]), 0.f);
            v.w = fmaxf(fmaf(v.w, sc[k4 + 3], sh[k4 + 3]), 0.f);
        }
        int pc = (k4 >> 2) ^ ((r >> 3) & 3);
        *(float4*)(As + r * 64 + (pc << 2)) = v;
    }
    for (int idx = t; idx < 1024; idx += 256) {
        *(float4*)(Ws + (idx << 2)) = *(const float4*)(W + (idx << 2));
    }
    __syncthreads();

    const int ci = t & 15;
    const int ri = t >> 4;
    const int c0 = ci << 2;

    float acc[8][4];
#pragma unroll
    for (int i = 0; i < 8; ++i) acc[i][0] = acc[i][1] = acc[i][2] = acc[i][3] = 0.f;

    const int pcx = ri & 3;
#pragma unroll 2
    for (int k4 = 0; k4 < 64; k4 += 4) {
        float4 wv[4];
        wv[0] = *(const float4*)(Ws + (k4 + 0) * 64 + c0);
        wv[1] = *(const float4*)(Ws + (k4 + 1) * 64 + c0);
        wv[2] = *(const float4*)(Ws + (k4 + 2) * 64 + c0);
        wv[3] = *(const float4*)(Ws + (k4 + 3) * 64 + c0);
        int pc = (k4 >> 2) ^ pcx;
#pragma unroll
        for (int i = 0; i < 8; ++i) {
            int r = ri * 8 + i;
            float4 av = *(const float4*)(As + r * 64 + (pc << 2));
            acc[i][0] += av.x * wv[0].x + av.y * wv[1].x + av.z * wv[2].x + av.w * wv[3].x;
            acc[i][1] += av.x * wv[0].y + av.y * wv[1].y + av.z * wv[2].y + av.w * wv[3].y;
            acc[i][2] += av.x * wv[0].z + av.y * wv[1].z + av.z * wv[2].z + av.w * wv[3].z;
            acc[i][3] += av.x * wv[0].w + av.y * wv[1].w + av.z * wv[2].w + av.w * wv[3].w;
        }
    }

    float bv0 = bias[c0 + 0], bv1 = bias[c0 + 1], bv2 = bias[c0 + 2], bv3 = bias[c0 + 3];
    float psum[4] = {0, 0, 0, 0}, psq[4] = {0, 0, 0, 0};
#pragma unroll
    for (int i = 0; i < 8; ++i) {
        int gr = rowbase + ri * 8 + i;
        if (gr < n) {
            float o0 = acc[i][0] + bv0;
            float o1 = acc[i][1] + bv1;
            float o2 = acc[i][2] + bv2;
            float o3 = acc[i][3] + bv3;
            *(float4*)(out + (size_t)gr * 64 + c0) = make_float4(o0, o1, o2, o3);
            psum[0] += o0; psq[0] += o0 * o0;
            psum[1] += o1; psq[1] += o1 * o1;
            psum[2] += o2; psq[2] += o2 * o2;
            psum[3] += o3; psq[3] += o3 * o3;
        }
    }

    __syncthreads();
    float* rsum = Ws;
    float* rsq = Ws + 64 * 17;
#pragma unroll
    for (int j = 0; j < 4; ++j) {
        rsum[(c0 + j) * 17 + ri] = psum[j];
        rsq[(c0 + j) * 17 + ri] = psq[j];
    }
    __syncthreads();
    if (t < 64) {
        float s = 0.f, q = 0.f;
#pragma unroll
        for (int i = 0; i < 16; ++i) {
            s += rsum[t * 17 + i];
            q += rsq[t * 17 + i];
        }
        atomicAdd(&stats_out[t], s);
        atomicAdd(&stats_out[64 + t], q);
    }
}

// ---------------- fused (BN+ReLU)? + pool + score : one block per graph ----------------
// mode 0: score = pool(h) @ pW + pb   (raw h, init score)
// mode 1: h = relu(bn(h)) in place; score += pool(h) @ pW + pb

__global__ __launch_bounds__(256) void pool_score_kernel(float* __restrict__ h,
                                                         const int* __restrict__ start,
                                                         const float* __restrict__ pW,
                                                         const float* __restrict__ pb,
                                                         float* __restrict__ score,
                                                         const float* __restrict__ stats,
                                                         const float* __restrict__ gamma,
                                                         const float* __restrict__ beta,
                                                         int n, int mode) {
    __shared__ float red[16][68];
    __shared__ float sc[64], sh[64], pl[64];
    const int t = threadIdx.x;
    const int g = blockIdx.x;
    if (mode && t < 64) {
        float inv_n = 1.0f / (float)n;
        float mean = stats[t] * inv_n;
        float var = stats[64 + t] * inv_n - mean * mean;
        float s = gamma[t] * rsqrtf(var + 1e-5f);
        sc[t] = s;
        sh[t] = beta[t] - mean * s;
    }
    __syncthreads();

    const int r16 = t >> 4;       // row offset 0..15
    const int q = t & 15;         // float4 index within 64-dim row
    const int k0 = q << 2;
    int i0 = start[g], i1 = start[g + 1];
    float4 ps = make_float4(0.f, 0.f, 0.f, 0.f);
    for (int i = i0 + r16; i < i1; i += 16) {
        float4 v = *(const float4*)(h + (size_t)i * 64 + k0);
        if (mode) {
            v.x = fmaxf(fmaf(v.x, sc[k0 + 0], sh[k0 + 0]), 0.f);
            v.y = fmaxf(fmaf(v.y, sc[k0 + 1], sh[k0 + 1]), 0.f);
            v.z = fmaxf(fmaf(v.z, sc[k0 + 2], sh[k0 + 2]), 0.f);
            v.w = fmaxf(fmaf(v.w, sc[k0 + 3], sh[k0 + 3]), 0.f);
            *(float4*)(h + (size_t)i * 64 + k0) = v;
        }
        ps.x += v.x; ps.y += v.y; ps.z += v.z; ps.w += v.w;
    }
    red[r16][k0 + 0] = ps.x;
    red[r16][k0 + 1] = ps.y;
    red[r16][k0 + 2] = ps.z;
    red[r16][k0 + 3] = ps.w;
    __syncthreads();
    if (t < 64) {
        float s = 0.f;
#pragma unroll
        for (int r = 0; r < 16; ++r) s += red[r][t];
        pl[t] = s;
    }
    __syncthreads();
    if (t < 16) {
        float s = pb[t];
#pragma unroll 8
        for (int d = 0; d < 64; ++d) s += pl[d] * pW[d * 16 + t];
        score[g * 16 + t] = mode ? (score[g * 16 + t] + s) : s;
    }
}

// ---------------- host ----------------

extern "C" void kernel_launch(void* const* d_in, const int* in_sizes, int n_in,
                              void* d_out, int out_size, void* d_ws, size_t ws_size,
                              hipStream_t stream) {
    const float* x = (const float*)d_in[0];
    const float* w = (const float*)d_in[1];
    const int* src = (const int*)d_in[2];
    const int* dst = (const int*)d_in[3];
    const int* gid = (const int*)d_in[4];
    const float* eps = (const float*)d_in[5];
    const float* W1 = (const float*)d_in[6];
    const float* b1 = (const float*)d_in[7];
    const float* bng = (const float*)d_in[8];
    const float* bnb = (const float*)d_in[9];
    const float* W2 = (const float*)d_in[10];
    const float* b2 = (const float*)d_in[11];
    const float* og = (const float*)d_in[12];
    const float* ob = (const float*)d_in[13];
    const float* pW = (const float*)d_in[14];
    const float* pb = (const float*)d_in[15];
    float* out = (float*)d_out;

    const int N = N_NODES, E = N_EDGES, G = N_GRAPHS;

    float* base = (float*)d_ws;
    float* HA = base;                      // N*64
    float* HB = HA + (size_t)N * 64;       // N*64
    float* stats = HB + (size_t)N * 64;    // 1024 (zeroed): 4 layers x 2 BNs x 128
    int* counts = (int*)(stats + 1024);    // N (zeroed)
    int* row_ptr = counts + N;             // N+1 (pad 4)
    int* cursor = row_ptr + N + 4;         // N+1 (pad 4)
    int2* pack = (int2*)(cursor + N + 4);  // E int2
    int* start = (int*)(pack + E);         // G+1 (pad to 132)
    int* bsum = start + 132;               // 256
    // total ~33 MB

    hipMemsetAsync(stats, 0, (size_t)(1024 + N) * sizeof(float), stream);

    // CSR build
    hipLaunchKernelGGL(count_kernel, dim3((E + 255) / 256), dim3(256), 0, stream, dst, counts, E);
    hipLaunchKernelGGL(bsum_kernel, dim3(SCAN_BLOCKS), dim3(256), 0, stream, counts, bsum, N);
    hipLaunchKernelGGL(bscan_kernel, dim3(1), dim3(256), 0, stream, bsum, SCAN_BLOCKS);
    hipLaunchKernelGGL(bwrite_kernel, dim3(SCAN_BLOCKS), dim3(256), 0, stream, counts, bsum,
                       row_ptr, cursor, N);
    hipLaunchKernelGGL(fill_kernel, dim3((E + 255) / 256), dim3(256), 0, stream, dst, src, w,
                       cursor, pack, E);
    hipLaunchKernelGGL(bounds_kernel, dim3((N + 255) / 256), dim3(256), 0, stream, gid, start, N, G);

    // layer-0 score on raw features
    hipLaunchKernelGGL(pool_score_kernel, dim3(G), dim3(256), 0, stream, (float*)x, start, pW, pb,
                       out, (const float*)nullptr, (const float*)nullptr, (const float*)nullptr,
                       N, 0);

    const float* cur = x;
    float* P = HA;
    float* Q = HB;
    for (int l = 0; l < 4; ++l) {
        hipLaunchKernelGGL(agg_kernel, dim3((N + 3) / 4), dim3(256), 0, stream, cur, pack,
                           row_ptr, eps, l, P, N);
        hipLaunchKernelGGL(gin_gemm64, dim3((N + TILE_ROWS - 1) / TILE_ROWS), dim3(256), 0, stream,
                           P, W1 + l * 4096, b1 + l * 64, Q, stats + l * 256,
                           (const float*)nullptr, (const float*)nullptr, (const float*)nullptr, N, 0);
        hipLaunchKernelGGL(gin_gemm64, dim3((N + TILE_ROWS - 1) / TILE_ROWS), dim3(256), 0, stream,
                           Q, W2 + l * 4096, b2 + l * 64, P, stats + l * 256 + 128,
                           stats + l * 256, bng + l * 64, bnb + l * 64, N, 1);
        hipLaunchKernelGGL(pool_score_kernel, dim3(G), dim3(256), 0, stream, P, start,
                           pW + (l + 1) * 1024, pb + (l + 1) * 16, out,
                           stats + l * 256 + 128, og + l * 64, ob + l * 64, N, 1);
        cur = P;
        float* tmp = P;
        P = Q;
        Q = tmp;
    }
}

// Round 3
// 551.190 us; speedup vs baseline: 1.5889x; 1.0967x over previous
//
#include <hip/hip_runtime.h>
#include <hip/hip_bf16.h>

#define N_NODES 50000
#define N_EDGES 800000
#define N_GRAPHS 128
#define NB 196            // coarse buckets of 256 nodes: ceil(50000/256)
#define EPB 4096          // edges per partition block
#define PART_BLOCKS ((N_EDGES + EPB - 1) / EPB)  // 196

// ---------------- two-level counting sort CSR build ----------------

// Pass A: coarse histogram (bucket = dst >> 8)
__global__ __launch_bounds__(256) void coarse_count_kernel(const int* __restrict__ dst,
                                                           int* __restrict__ cc, int E) {
    __shared__ int lh[NB];
    int t = threadIdx.x;
    for (int i = t; i < NB; i += 256) lh[i] = 0;
    __syncthreads();
    int base = blockIdx.x * EPB;
#pragma unroll
    for (int i = 0; i < EPB / 256; ++i) {
        int e = base + i * 256 + t;
        if (e < E) atomicAdd(&lh[dst[e] >> 8], 1);
    }
    __syncthreads();
    for (int i = t; i < NB; i += 256) {
        int v = lh[i];
        if (v) atomicAdd(&cc[i], v);
    }
}

// Pass B: exclusive scan of NB coarse counts -> cbase[0..NB], cursor copy
__global__ __launch_bounds__(256) void coarse_scan_kernel(const int* __restrict__ cc,
                                                          int* __restrict__ cbase,
                                                          int* __restrict__ cursor, int E) {
    __shared__ int s[256];
    int t = threadIdx.x;
    int v = (t < NB) ? cc[t] : 0;
    s[t] = v;
    __syncthreads();
    for (int off = 1; off < 256; off <<= 1) {
        int u = (t >= off) ? s[t - off] : 0;
        __syncthreads();
        s[t] += u;
        __syncthreads();
    }
    if (t < NB) {
        int excl = s[t] - v;
        cbase[t] = excl;
        cursor[t] = excl;
    }
    if (t == 0) cbase[NB] = E;
}

// Pass C: partition edges into bucket-contiguous tmp, payload = (src | dl<<16, w)
__global__ __launch_bounds__(256) void partition_kernel(const int* __restrict__ dst,
                                                        const int* __restrict__ src,
                                                        const float* __restrict__ w,
                                                        int* __restrict__ cursor,
                                                        int2* __restrict__ tmp, int E) {
    __shared__ int lh[NB];
    __shared__ int lbase[NB];
    int t = threadIdx.x;
    for (int i = t; i < NB; i += 256) lh[i] = 0;
    __syncthreads();
    int base = blockIdx.x * EPB;
    int d[EPB / 256];
#pragma unroll
    for (int i = 0; i < EPB / 256; ++i) {
        int e = base + i * 256 + t;
        d[i] = (e < E) ? dst[e] : -1;
        if (d[i] >= 0) atomicAdd(&lh[d[i] >> 8], 1);
    }
    __syncthreads();
    for (int i = t; i < NB; i += 256) {
        int v = lh[i];
        if (v) lbase[i] = atomicAdd(&cursor[i], v);
        lh[i] = 0;  // reuse as run counter
    }
    __syncthreads();
#pragma unroll
    for (int i = 0; i < EPB / 256; ++i) {
        int e = base + i * 256 + t;
        if (d[i] >= 0) {
            int b = d[i] >> 8;
            int dl = d[i] & 255;
            int rank = atomicAdd(&lh[b], 1);
            int pos = lbase[b] + rank;
            tmp[pos] = make_int2(src[e] | (dl << 16), __float_as_int(w[e]));
        }
    }
}

// Pass D: within-bucket sort by node -> final pack + row_ptr
__global__ __launch_bounds__(256) void bucket_sort_kernel(const int2* __restrict__ tmp,
                                                          const int* __restrict__ cbase,
                                                          int* __restrict__ row_ptr,
                                                          int2* __restrict__ pack, int n) {
    __shared__ int hist[256];
    __shared__ int run[256];
    int t = threadIdx.x;
    int b = blockIdx.x;
    int e0 = cbase[b], e1 = cbase[b + 1];
    hist[t] = 0;
    __syncthreads();
    for (int j = e0 + t; j < e1; j += 256) {
        int dl = (tmp[j].x >> 16) & 255;
        atomicAdd(&hist[dl], 1);
    }
    __syncthreads();
    int v = hist[t];
    __shared__ int s[256];
    s[t] = v;
    __syncthreads();
    for (int off = 1; off < 256; off <<= 1) {
        int u = (t >= off) ? s[t - off] : 0;
        __syncthreads();
        s[t] += u;
        __syncthreads();
    }
    int excl = s[t] - v;
    int node = b * 256 + t;
    if (node < n) row_ptr[node] = e0 + excl;
    if (b == gridDim.x - 1 && t == 0) row_ptr[n] = e1;
    run[t] = e0 + excl;
    __syncthreads();
    for (int j = e0 + t; j < e1; j += 256) {
        int2 p = tmp[j];
        int dl = (p.x >> 16) & 255;
        int pos = atomicAdd(&run[dl], 1);
        pack[pos] = make_int2(p.x & 0xFFFF, p.y);
    }
}

// ---------------- graph segment boundaries (graph_ids sorted) ----------------

__global__ void bounds_kernel(const int* __restrict__ gid, int* __restrict__ start,
                              int n, int ngraphs) {
    int i = blockIdx.x * blockDim.x + threadIdx.x;
    if (i >= n) return;
    int g = gid[i];
    if (i == 0) {
        for (int q = 0; q <= g; ++q) start[q] = 0;
    } else {
        int p = gid[i - 1];
        if (p != g) {
            for (int q = p + 1; q <= g; ++q) start[q] = i;
        }
    }
    if (i == n - 1) {
        for (int q = g + 1; q <= ngraphs; ++q) start[q] = n;
    }
}

// ---------------- edge aggregation: one wave per node ----------------

__global__ __launch_bounds__(256) void agg_kernel(const float* __restrict__ h,
                                                  const int2* __restrict__ pack,
                                                  const int* __restrict__ row_ptr,
                                                  const float* __restrict__ eps, int layer,
                                                  float* __restrict__ out, int n) {
    int node = blockIdx.x * 4 + (threadIdx.x >> 6);
    int d = threadIdx.x & 63;
    if (node >= n) return;
    float e1 = 1.0f + eps[layer];
    float acc = e1 * h[(size_t)node * 64 + d];
    int j = row_ptr[node];
    int j1 = row_ptr[node + 1];
    for (; j + 3 < j1; j += 4) {
        int2 p0 = pack[j];
        int2 p1 = pack[j + 1];
        int2 p2 = pack[j + 2];
        int2 p3 = pack[j + 3];
        float h0 = h[(size_t)p0.x * 64 + d];
        float h1 = h[(size_t)p1.x * 64 + d];
        float h2 = h[(size_t)p2.x * 64 + d];
        float h3 = h[(size_t)p3.x * 64 + d];
        acc += __int_as_float(p0.y) * h0;
        acc += __int_as_float(p1.y) * h1;
        acc += __int_as_float(p2.y) * h2;
        acc += __int_as_float(p3.y) * h3;
    }
    for (; j < j1; ++j) {
        int2 p = pack[j];
        acc += __int_as_float(p.y) * h[(size_t)p.x * 64 + d];
    }
    out[(size_t)node * 64 + d] = acc;
}

// ---------------- 64-wide GEMM with fused BN-stat accumulation ----------------

#define TILE_ROWS 128

__global__ __launch_bounds__(256) void gin_gemm64(const float* __restrict__ A,
                                                  const float* __restrict__ W,
                                                  const float* __restrict__ bias,
                                                  float* __restrict__ out,
                                                  float* __restrict__ stats_out,
                                                  const float* __restrict__ stats_in,
                                                  const float* __restrict__ gamma,
                                                  const float* __restrict__ beta,
                                                  int n, int transform) {
    __shared__ float smem[TILE_ROWS * 64 + 64 * 64 + 128];
    float* As = smem;                   // swizzled [128][64]
    float* Ws = smem + TILE_ROWS * 64;  // [64][64]
    float* sc = Ws + 4096;
    float* sh = sc + 64;

    const int t = threadIdx.x;
    const int rowbase = blockIdx.x * TILE_ROWS;

    if (transform && t < 64) {
        float inv_n = 1.0f / (float)n;
        float mean = stats_in[t] * inv_n;
        float var = stats_in[64 + t] * inv_n - mean * mean;
        float s = gamma[t] * rsqrtf(var + 1e-5f);
        sc[t] = s;
        sh[t] = beta[t] - mean * s;
    }
    __syncthreads();

    for (int idx = t; idx < TILE_ROWS * 16; idx += 256) {
        int r = idx >> 4;
        int k4 = (idx & 15) << 2;
        int gr = rowbase + r;
        float4 v = make_float4(0.f, 0.f, 0.f, 0.f);
        if (gr < n) v = *(const float4*)(A + (size_t)gr * 64 + k4);
        if (transform) {
            v.x = fmaxf(fmaf(v.x, sc[k4 + 0], sh[k4 + 0]), 0.f);
            v.y = fmaxf(fmaf(v.y, sc[k4 + 1], sh[k4 + 1]), 0.f);
            v.z = fmaxf(fmaf(v.z, sc[k4 + 2], sh[k4 + 2]), 0.f);
            v.w = fmaxf(fmaf(v.w, sc[k4 + 3], sh[k4 + 3]), 0.f);
        }
        int pc = (k4 >> 2) ^ ((r >> 3) & 3);
        *(float4*)(As + r * 64 + (pc << 2)) = v;
    }
    for (int idx = t; idx < 1024; idx += 256) {
        *(float4*)(Ws + (idx << 2)) = *(const float4*)(W + (idx << 2));
    }
    __syncthreads();

    const int ci = t & 15;
    const int ri = t >> 4;
    const int c0 = ci << 2;

    float acc[8][4];
#pragma unroll
    for (int i = 0; i < 8; ++i) acc[i][0] = acc[i][1] = acc[i][2] = acc[i][3] = 0.f;

    const int pcx = ri & 3;
#pragma unroll 2
    for (int k4 = 0; k4 < 64; k4 += 4) {
        float4 wv[4];
        wv[0] = *(const float4*)(Ws + (k4 + 0) * 64 + c0);
        wv[1] = *(const float4*)(Ws + (k4 + 1) * 64 + c0);
        wv[2] = *(const float4*)(Ws + (k4 + 2) * 64 + c0);
        wv[3] = *(const float4*)(Ws + (k4 + 3) * 64 + c0);
        int pc = (k4 >> 2) ^ pcx;
#pragma unroll
        for (int i = 0; i < 8; ++i) {
            int r = ri * 8 + i;
            float4 av = *(const float4*)(As + r * 64 + (pc << 2));
            acc[i][0] += av.x * wv[0].x + av.y * wv[1].x + av.z * wv[2].x + av.w * wv[3].x;
            acc[i][1] += av.x * wv[0].y + av.y * wv[1].y + av.z * wv[2].y + av.w * wv[3].y;
            acc[i][2] += av.x * wv[0].z + av.y * wv[1].z + av.z * wv[2].z + av.w * wv[3].z;
            acc[i][3] += av.x * wv[0].w + av.y * wv[1].w + av.z * wv[2].w + av.w * wv[3].w;
        }
    }

    float bv0 = bias[c0 + 0], bv1 = bias[c0 + 1], bv2 = bias[c0 + 2], bv3 = bias[c0 + 3];
    float psum[4] = {0, 0, 0, 0}, psq[4] = {0, 0, 0, 0};
#pragma unroll
    for (int i = 0; i < 8; ++i) {
        int gr = rowbase + ri * 8 + i;
        if (gr < n) {
            float o0 = acc[i][0] + bv0;
            float o1 = acc[i][1] + bv1;
            float o2 = acc[i][2] + bv2;
            float o3 = acc[i][3] + bv3;
            *(float4*)(out + (size_t)gr * 64 + c0) = make_float4(o0, o1, o2, o3);
            psum[0] += o0; psq[0] += o0 * o0;
            psum[1] += o1; psq[1] += o1 * o1;
            psum[2] += o2; psq[2] += o2 * o2;
            psum[3] += o3; psq[3] += o3 * o3;
        }
    }

    __syncthreads();
    float* rsum = Ws;
    float* rsq = Ws + 64 * 17;
#pragma unroll
    for (int j = 0; j < 4; ++j) {
        rsum[(c0 + j) * 17 + ri] = psum[j];
        rsq[(c0 + j) * 17 + ri] = psq[j];
    }
    __syncthreads();
    if (t < 64) {
        float s = 0.f, q = 0.f;
#pragma unroll
        for (int i = 0; i < 16; ++i) {
            s += rsum[t * 17 + i];
            q += rsq[t * 17 + i];
        }
        atomicAdd(&stats_out[t], s);
        atomicAdd(&stats_out[64 + t], q);
    }
}

// ---------------- fused (BN+ReLU)? + pool + score : one block per graph ----------------

__global__ __launch_bounds__(256) void pool_score_kernel(float* __restrict__ h,
                                                         const int* __restrict__ start,
                                                         const float* __restrict__ pW,
                                                         const float* __restrict__ pb,
                                                         float* __restrict__ score,
                                                         const float* __restrict__ stats,
                                                         const float* __restrict__ gamma,
                                                         const float* __restrict__ beta,
                                                         int n, int mode) {
    __shared__ float red[16][68];
    __shared__ float sc[64], sh[64], pl[64];
    const int t = threadIdx.x;
    const int g = blockIdx.x;
    if (mode && t < 64) {
        float inv_n = 1.0f / (float)n;
        float mean = stats[t] * inv_n;
        float var = stats[64 + t] * inv_n - mean * mean;
        float s = gamma[t] * rsqrtf(var + 1e-5f);
        sc[t] = s;
        sh[t] = beta[t] - mean * s;
    }
    __syncthreads();

    const int r16 = t >> 4;
    const int q = t & 15;
    const int k0 = q << 2;
    int i0 = start[g], i1 = start[g + 1];
    float4 ps = make_float4(0.f, 0.f, 0.f, 0.f);
    for (int i = i0 + r16; i < i1; i += 16) {
        float4 v = *(const float4*)(h + (size_t)i * 64 + k0);
        if (mode) {
            v.x = fmaxf(fmaf(v.x, sc[k0 + 0], sh[k0 + 0]), 0.f);
            v.y = fmaxf(fmaf(v.y, sc[k0 + 1], sh[k0 + 1]), 0.f);
            v.z = fmaxf(fmaf(v.z, sc[k0 + 2], sh[k0 + 2]), 0.f);
            v.w = fmaxf(fmaf(v.w, sc[k0 + 3], sh[k0 + 3]), 0.f);
            *(float4*)(h + (size_t)i * 64 + k0) = v;
        }
        ps.x += v.x; ps.y += v.y; ps.z += v.z; ps.w += v.w;
    }
    red[r16][k0 + 0] = ps.x;
    red[r16][k0 + 1] = ps.y;
    red[r16][k0 + 2] = ps.z;
    red[r16][k0 + 3] = ps.w;
    __syncthreads();
    if (t < 64) {
        float s = 0.f;
#pragma unroll
        for (int r = 0; r < 16; ++r) s += red[r][t];
        pl[t] = s;
    }
    __syncthreads();
    if (t < 16) {
        float s = pb[t];
#pragma unroll 8
        for (int d = 0; d < 64; ++d) s += pl[d] * pW[d * 16 + t];
        score[g * 16 + t] = mode ? (score[g * 16 + t] + s) : s;
    }
}

// ---------------- host ----------------

extern "C" void kernel_launch(void* const* d_in, const int* in_sizes, int n_in,
                              void* d_out, int out_size, void* d_ws, size_t ws_size,
                              hipStream_t stream) {
    const float* x = (const float*)d_in[0];
    const float* w = (const float*)d_in[1];
    const int* src = (const int*)d_in[2];
    const int* dst = (const int*)d_in[3];
    const int* gid = (const int*)d_in[4];
    const float* eps = (const float*)d_in[5];
    const float* W1 = (const float*)d_in[6];
    const float* b1 = (const float*)d_in[7];
    const float* bng = (const float*)d_in[8];
    const float* bnb = (const float*)d_in[9];
    const float* W2 = (const float*)d_in[10];
    const float* b2 = (const float*)d_in[11];
    const float* og = (const float*)d_in[12];
    const float* ob = (const float*)d_in[13];
    const float* pW = (const float*)d_in[14];
    const float* pb = (const float*)d_in[15];
    float* out = (float*)d_out;

    const int N = N_NODES, E = N_EDGES, G = N_GRAPHS;

    float* base = (float*)d_ws;
    float* HA = base;                      // N*64
    float* HB = HA + (size_t)N * 64;       // N*64
    float* stats = HB + (size_t)N * 64;    // 1024 floats (zeroed)
    int* cc = (int*)(stats + 1024);        // NB coarse counts (zeroed)
    int* cbase = cc + NB;                  // NB+1
    int* cursor = cbase + NB + 4;          // NB
    int* row_ptr = cursor + NB + 4;        // N+1 (pad)
    int* start = row_ptr + N + 8;          // G+1 (pad to 132)
    int2* tmp = (int2*)(start + 132);      // E int2
    int2* pack = tmp + E;                  // E int2
    // total ~38.5 MB

    // zero only stats + coarse counts (~5 KB)
    hipMemsetAsync(stats, 0, (size_t)(1024 + NB) * sizeof(float), stream);

    // CSR build: two-level counting sort
    hipLaunchKernelGGL(coarse_count_kernel, dim3(PART_BLOCKS), dim3(256), 0, stream, dst, cc, E);
    hipLaunchKernelGGL(coarse_scan_kernel, dim3(1), dim3(256), 0, stream, cc, cbase, cursor, E);
    hipLaunchKernelGGL(partition_kernel, dim3(PART_BLOCKS), dim3(256), 0, stream, dst, src, w,
                       cursor, tmp, E);
    hipLaunchKernelGGL(bucket_sort_kernel, dim3(NB), dim3(256), 0, stream, tmp, cbase, row_ptr,
                       pack, N);
    hipLaunchKernelGGL(bounds_kernel, dim3((N + 255) / 256), dim3(256), 0, stream, gid, start, N, G);

    // layer-0 score on raw features
    hipLaunchKernelGGL(pool_score_kernel, dim3(G), dim3(256), 0, stream, (float*)x, start, pW, pb,
                       out, (const float*)nullptr, (const float*)nullptr, (const float*)nullptr,
                       N, 0);

    const float* cur = x;
    float* P = HA;
    float* Q = HB;
    for (int l = 0; l < 4; ++l) {
        hipLaunchKernelGGL(agg_kernel, dim3((N + 3) / 4), dim3(256), 0, stream, cur, pack,
                           row_ptr, eps, l, P, N);
        hipLaunchKernelGGL(gin_gemm64, dim3((N + TILE_ROWS - 1) / TILE_ROWS), dim3(256), 0, stream,
                           P, W1 + l * 4096, b1 + l * 64, Q, stats + l * 256,
                           (const float*)nullptr, (const float*)nullptr, (const float*)nullptr, N, 0);
        hipLaunchKernelGGL(gin_gemm64, dim3((N + TILE_ROWS - 1) / TILE_ROWS), dim3(256), 0, stream,
                           Q, W2 + l * 4096, b2 + l * 64, P, stats + l * 256 + 128,
                           stats + l * 256, bng + l * 64, bnb + l * 64, N, 1);
        hipLaunchKernelGGL(pool_score_kernel, dim3(G), dim3(256), 0, stream, P, start,
                           pW + (l + 1) * 1024, pb + (l + 1) * 16, out,
                           stats + l * 256 + 128, og + l * 64, ob + l * 64, N, 1);
        cur = P;
        float* tmp2 = P;
        P = Q;
        Q = tmp2;
    }
}